// Round 4
// baseline (1401.141 us; speedup 1.0000x reference)
//
#include <hip/hip_runtime.h>
#include <hip/hip_bf16.h>

// Problem constants
#define R_ 256
#define N_ 2048
#define K_ 64
#define C_ 16
#define D_ 64
#define H_ 128
#define EPS_ 1e-5f

// Critic partitioning: 16 chunks of 128 nodes
#define CH_ 16
#define NB_ 128

// LDS row strides (ushorts). 16B-aligned rows; non-pow2 shift vs banks.
#define XST_ 72     // rows of 64 bf16
#define TST_ 136    // rows of 128 bf16

typedef short bf16x8 __attribute__((ext_vector_type(8)));
typedef float f32x4  __attribute__((ext_vector_type(4)));

__device__ __forceinline__ unsigned short f2b(float f) {
    union { float f; unsigned int u; } v; v.f = f;
    unsigned int u = v.u;
    unsigned int r = (u + 0x7FFFu + ((u >> 16) & 1u)) >> 16;
    return (unsigned short)r;
}
__device__ __forceinline__ unsigned int pk2(float a, float b) {
    return (unsigned int)f2b(a) | ((unsigned int)f2b(b) << 16);
}

// workspace layout:
//   part : R_*CH_*(H_+2) floats                  (byte off 0)
//   wsW1 : 24576 ushort (B-frag swizzled W_phi1) (after part)
//   wsW2 : 16384 ushort
//   wsWe : 8192 ushort  (W_enc_c)
//   cnt  : 256 int      (per-row done counters)
#define PART_FLOATS (R_ * CH_ * (H_ + 2))
#define W1_USHORTS  24576
#define W2_USHORTS  16384
#define WE_USHORTS  8192

// Fused-kernel LDS: actor = 4 waves x 7168 B; critic = 21516 B. max = 28672.
#define AW_STRIDE 7168
#define SMEM_BYTES 28672

// ---------------------------------------------------------------------------
// Prep: fp32 weights -> bf16, pre-swizzled per-lane B-fragment order; zero
// the per-row done counters (ws is re-poisoned 0xAA before every launch).
// out[(nt*KS+ks)*512 + l*8 + j] = W[ks*32 + (l>>4)*8 + j][nt*16 + (l&15)]
// ---------------------------------------------------------------------------
__global__ __launch_bounds__(256) void prep_kernel(
    const float* __restrict__ W_phi1, const float* __restrict__ W_phi2,
    const float* __restrict__ W_enc_c,
    unsigned short* __restrict__ o1, unsigned short* __restrict__ o2,
    unsigned short* __restrict__ oe, int* __restrict__ cnt)
{
    const int i = blockIdx.x * 256 + threadIdx.x;
    const int j = i & 7, l = (i >> 3) & 63, t = i >> 9;
    const int k_off = ((l >> 4) << 3) + j;
    const int n_off = l & 15;
    if (i < W1_USHORTS) {
        const int ks = t % 6, nt = t / 6;
        o1[i] = f2b(W_phi1[(ks * 32 + k_off) * H_ + nt * 16 + n_off]);
    }
    if (i < W2_USHORTS) {
        const int ks = t & 3, nt = t >> 2;
        o2[i] = f2b(W_phi2[(ks * 32 + k_off) * H_ + nt * 16 + n_off]);
    }
    if (i < WE_USHORTS) {
        const int ks = t & 1, nt = t >> 1;
        oe[i] = f2b(W_enc_c[(ks * 32 + k_off) * H_ + nt * 16 + n_off]);
    }
    if (i < R_) cnt[i] = 0;
}

// ---------------------------------------------------------------------------
// Fused kernel. Even blocks: actor (4 independent waves, one (r,k) each,
// barrier-free). Odd blocks: critic partial for one (r, 128-node chunk);
// the last chunk-block of a row also runs the critic head (atomic counter).
// ---------------------------------------------------------------------------
__global__ __launch_bounds__(256) void fused_kernel(
    const float* __restrict__ x, const int* __restrict__ cand_idx,
    const int* __restrict__ comp_idx,
    const float* __restrict__ W_enc_a, const float* __restrict__ b_enc_a,
    const float* __restrict__ b_enc_c,
    const float* __restrict__ ln_g, const float* __restrict__ ln_b,
    const float* __restrict__ W_actor, const float* __restrict__ b_actor,
    const float* __restrict__ b_phi1, const float* __restrict__ b_phi2,
    const float* __restrict__ w_score, const float* __restrict__ w_comp,
    const float* __restrict__ comp_bias,
    const float* __restrict__ w_attn, const float* __restrict__ b_attn,
    const float* __restrict__ W_crit1, const float* __restrict__ b_crit1,
    const float* __restrict__ W_crit2, const float* __restrict__ b_crit2,
    const unsigned short* __restrict__ wsW1, const unsigned short* __restrict__ wsW2,
    const unsigned short* __restrict__ wsWe,
    float* __restrict__ part, int* __restrict__ cnt,
    float* __restrict__ logits, float* __restrict__ values)
{
    __shared__ __align__(16) char smem[SMEM_BYTES];
    const int tid = threadIdx.x;
    const int wv = tid >> 6, lane = tid & 63;
    const int q = lane >> 4, ln15 = lane & 15;

    if ((blockIdx.x & 1) == 0) {
        // ================= ACTOR: wave wv handles rk =================
        const int rk = (blockIdx.x >> 1) * 4 + wv;
        const int r = rk >> 6;   // / K_
        char* wbase = smem + wv * AW_STRIDE;
        float*          xrow = (float*)wbase;                       // 256 B
        unsigned short* hnb  = (unsigned short*)(wbase + 256);      // 256 B
        unsigned short* xc   = (unsigned short*)(wbase + 512);      // 2304 B
        unsigned short* t1   = (unsigned short*)(wbase + 2816);     // 4352 B

        // stage candidate row (fp32) — lanes 0..15
        const int ci = cand_idx[rk];
        if (lane < 16) {
            const float4 v = *(const float4*)&x[((long)r * N_ + ci) * D_ + lane * 4];
            *(float4*)&xrow[lane * 4] = v;
        }
        // stage 16 competitor rows (bf16)
        #pragma unroll
        for (int i = 0; i < 4; ++i) {
            const int flat = i * 64 + lane;
            const int c = flat >> 4, d0 = (flat & 15) * 4;
            const int idx = comp_idx[rk * C_ + c];
            const float4 v = *(const float4*)&x[((long)r * N_ + idx) * D_ + d0];
            uint2 w; w.x = pk2(v.x, v.y); w.y = pk2(v.z, v.w);
            *(uint2*)&xc[c * XST_ + d0] = w;
        }
        __builtin_amdgcn_wave_barrier();

        // fp32 encode at candidate: lane -> h = lane, lane+64
        float h0 = b_enc_a[lane], h1 = b_enc_a[lane + 64];
        #pragma unroll 8
        for (int d = 0; d < D_; ++d) {
            const float xv = xrow[d];   // LDS broadcast
            h0 = fmaf(xv, W_enc_a[d * H_ + lane], h0);
            h1 = fmaf(xv, W_enc_a[d * H_ + 64 + lane], h1);
        }
        h0 = fmaxf(h0, 0.f); h1 = fmaxf(h1, 0.f);

        // LayerNorm (wave butterfly)
        float s = h0 + h1, s2 = h0 * h0 + h1 * h1;
        #pragma unroll
        for (int o = 1; o <= 32; o <<= 1) {
            s  += __shfl_xor(s, o);
            s2 += __shfl_xor(s2, o);
        }
        const float mu = s * (1.f / H_);
        const float rstd = rsqrtf(s2 * (1.f / H_) - mu * mu + EPS_);
        const float v0 = (h0 - mu) * rstd * ln_g[lane]      + ln_b[lane];
        const float v1 = (h1 - mu) * rstd * ln_g[lane + 64] + ln_b[lane + 64];
        hnb[lane]      = f2b(v0);
        hnb[lane + 64] = f2b(v1);

        // base head
        float base_l = v0 * W_actor[lane] + v1 * W_actor[lane + 64];
        #pragma unroll
        for (int o = 1; o <= 32; o <<= 1) base_l += __shfl_xor(base_l, o);
        __builtin_amdgcn_wave_barrier();

        // phi1 MFMA: A=[16x192] rows = [hn | xc_c]; all 8 n-tiles this wave
        bf16x8 a1[6];
        #pragma unroll
        for (int ks = 0; ks < 4; ++ks)
            a1[ks] = *(const bf16x8*)&hnb[ks * 32 + q * 8];        // broadcast rows
        #pragma unroll
        for (int ks = 0; ks < 2; ++ks)
            a1[4 + ks] = *(const bf16x8*)&xc[ln15 * XST_ + ks * 32 + q * 8];

        const bf16x8* W1f = (const bf16x8*)wsW1;
        const bf16x8* W2f = (const bf16x8*)wsW2;

        f32x4 acc1[8];
        #pragma unroll
        for (int nt = 0; nt < 8; ++nt) acc1[nt] = (f32x4){0.f,0.f,0.f,0.f};
        #pragma unroll
        for (int nt = 0; nt < 8; ++nt)
            #pragma unroll
            for (int ks = 0; ks < 6; ++ks) {
                const bf16x8 b = W1f[(nt * 6 + ks) * 64 + lane];
                acc1[nt] = __builtin_amdgcn_mfma_f32_16x16x32_bf16(a1[ks], b, acc1[nt], 0, 0, 0);
            }
        // bias + relu -> t1 (bf16), C/D layout: row=q*4+reg (comp), col=h
        #pragma unroll
        for (int nt = 0; nt < 8; ++nt) {
            const int h = nt * 16 + ln15;
            const float b1 = b_phi1[h];
            #pragma unroll
            for (int reg = 0; reg < 4; ++reg)
                t1[(q * 4 + reg) * TST_ + h] = f2b(fmaxf(acc1[nt][reg] + b1, 0.f));
        }
        __builtin_amdgcn_wave_barrier();

        // phi2 MFMA: [16x128]@[128x128]
        bf16x8 a2[4];
        #pragma unroll
        for (int ks = 0; ks < 4; ++ks)
            a2[ks] = *(const bf16x8*)&t1[ln15 * TST_ + ks * 32 + q * 8];
        f32x4 acc2[8];
        #pragma unroll
        for (int nt = 0; nt < 8; ++nt) acc2[nt] = (f32x4){0.f,0.f,0.f,0.f};
        #pragma unroll
        for (int nt = 0; nt < 8; ++nt)
            #pragma unroll
            for (int ks = 0; ks < 4; ++ks) {
                const bf16x8 b = W2f[(nt * 4 + ks) * 64 + lane];
                acc2[nt] = __builtin_amdgcn_mfma_f32_16x16x32_bf16(a2[ks], b, acc2[nt], 0, 0, 0);
            }

        // heads: s[c] = z2.w_score, q[c] = z2.w_comp (z2 = acc2 + b_phi2)
        float sp[4] = {0.f,0.f,0.f,0.f}, qp[4] = {0.f,0.f,0.f,0.f};
        #pragma unroll
        for (int nt = 0; nt < 8; ++nt) {
            const int h = nt * 16 + ln15;
            const float ws = w_score[h], wc = w_comp[h], b2 = b_phi2[h];
            #pragma unroll
            for (int reg = 0; reg < 4; ++reg) {
                const float z = acc2[nt][reg] + b2;
                sp[reg] = fmaf(z, ws, sp[reg]);
                qp[reg] = fmaf(z, wc, qp[reg]);
            }
        }
        #pragma unroll
        for (int reg = 0; reg < 4; ++reg)
            #pragma unroll
            for (int m = 1; m <= 8; m <<= 1) {
                sp[reg] += __shfl_xor(sp[reg], m);
                qp[reg] += __shfl_xor(qp[reg], m);
            }
        // softmax over 16 comps distributed as c = q*4+reg
        float mloc = fmaxf(fmaxf(sp[0], sp[1]), fmaxf(sp[2], sp[3]));
        mloc = fmaxf(mloc, __shfl_xor(mloc, 16));
        mloc = fmaxf(mloc, __shfl_xor(mloc, 32));
        float S = 0.f, V = 0.f;
        #pragma unroll
        for (int reg = 0; reg < 4; ++reg) {
            const float e = __expf(sp[reg] - mloc);
            S += e; V = fmaf(e, qp[reg], V);
        }
        S += __shfl_xor(S, 16); S += __shfl_xor(S, 32);
        V += __shfl_xor(V, 16); V += __shfl_xor(V, 32);
        if (lane == 0)
            logits[rk] = base_l + V / S + comp_bias[0];

    } else {
        // ================= CRITIC: block = (r, 128-node chunk) =================
        const int cid = blockIdx.x >> 1;
        const int r = cid >> 4, ch = cid & 15;
        unsigned short* xt = (unsigned short*)smem;            // 18432 B
        float* sc    = (float*)(smem + 18432);                 // 512 B
        float* ebuf  = (float*)(smem + 18944);                 // 512 B
        float (*gbuf)[H_] = (float(*)[H_])(smem + 19456);      // 2048 B
        float* red   = (float*)(smem + 21504);                 // 8 B
        int*   sflag = (int*)(smem + 21512);

        // stage x chunk -> bf16 LDS
        const float4* xb = (const float4*)(x + ((long)r * N_ + (long)ch * NB_) * D_);
        for (int i = tid; i < NB_ * 16; i += 256) {
            const int row = i >> 4, d0 = (i & 15) * 4;
            const float4 v = xb[i];
            uint2 w; w.x = pk2(v.x, v.y); w.y = pk2(v.z, v.w);
            *(uint2*)&xt[row * XST_ + d0] = w;
        }
        __syncthreads();

        bf16x8 A[2][2];
        #pragma unroll
        for (int mti = 0; mti < 2; ++mti) {
            const int node = (wv * 2 + mti) * 16 + ln15;
            #pragma unroll
            for (int ks = 0; ks < 2; ++ks)
                A[mti][ks] = *(const bf16x8*)&xt[node * XST_ + ks * 32 + q * 8];
        }
        float wa[8], be[8];
        #pragma unroll
        for (int nt = 0; nt < 8; ++nt) {
            wa[nt] = w_attn[nt * 16 + ln15];
            be[nt] = b_enc_c[nt * 16 + ln15];
        }
        const float batt = b_attn[0];
        const bf16x8* Wef = (const bf16x8*)wsWe;
        f32x4 acc[2][8];
        #pragma unroll
        for (int mti = 0; mti < 2; ++mti)
            #pragma unroll
            for (int nt = 0; nt < 8; ++nt)
                acc[mti][nt] = (f32x4){0.f,0.f,0.f,0.f};
        #pragma unroll
        for (int nt = 0; nt < 8; ++nt)
            #pragma unroll
            for (int ks = 0; ks < 2; ++ks) {
                const bf16x8 b = Wef[(nt * 2 + ks) * 64 + lane];
                acc[0][nt] = __builtin_amdgcn_mfma_f32_16x16x32_bf16(A[0][ks], b, acc[0][nt], 0, 0, 0);
                acc[1][nt] = __builtin_amdgcn_mfma_f32_16x16x32_bf16(A[1][ks], b, acc[1][nt], 0, 0, 0);
            }
        #pragma unroll
        for (int mti = 0; mti < 2; ++mti)
            #pragma unroll
            for (int nt = 0; nt < 8; ++nt)
                #pragma unroll
                for (int reg = 0; reg < 4; ++reg)
                    acc[mti][nt][reg] = fmaxf(acc[mti][nt][reg] + be[nt], 0.f);

        // sc[node] = h.w_attn + b_attn
        #pragma unroll
        for (int mti = 0; mti < 2; ++mti)
            #pragma unroll
            for (int reg = 0; reg < 4; ++reg) {
                float sv = 0.f;
                #pragma unroll
                for (int nt = 0; nt < 8; ++nt)
                    sv = fmaf(acc[mti][nt][reg], wa[nt], sv);
                #pragma unroll
                for (int m = 1; m <= 8; m <<= 1) sv += __shfl_xor(sv, m);
                if (ln15 == 0)
                    sc[(wv * 2 + mti) * 16 + q * 4 + reg] = sv + batt;
            }
        __syncthreads();

        if (tid < 64) {
            const float u0 = sc[tid], u1 = sc[tid + 64];
            float m = fmaxf(u0, u1);
            #pragma unroll
            for (int o = 1; o <= 32; o <<= 1) m = fmaxf(m, __shfl_xor(m, o));
            float ssum = __expf(u0 - m) + __expf(u1 - m);
            #pragma unroll
            for (int o = 1; o <= 32; o <<= 1) ssum += __shfl_xor(ssum, o);
            if (tid == 0) { red[0] = m; red[1] = ssum; }
        }
        __syncthreads();
        const float mstar = red[0];
        if (tid < NB_) ebuf[tid] = __expf(sc[tid] - mstar);
        __syncthreads();

        float gp[8] = {0.f,0.f,0.f,0.f,0.f,0.f,0.f,0.f};
        #pragma unroll
        for (int mti = 0; mti < 2; ++mti)
            #pragma unroll
            for (int reg = 0; reg < 4; ++reg) {
                const float e = ebuf[(wv * 2 + mti) * 16 + q * 4 + reg];
                #pragma unroll
                for (int nt = 0; nt < 8; ++nt)
                    gp[nt] = fmaf(e, acc[mti][nt][reg], gp[nt]);
            }
        #pragma unroll
        for (int nt = 0; nt < 8; ++nt) {
            float v = gp[nt];
            v += __shfl_xor(v, 16);
            v += __shfl_xor(v, 32);
            if (q == 0) gbuf[wv][nt * 16 + ln15] = v;
        }
        __syncthreads();

        float* pr = part + ((long)r * CH_ + ch) * (H_ + 2);
        if (tid < H_)
            pr[2 + tid] = gbuf[0][tid] + gbuf[1][tid] + gbuf[2][tid] + gbuf[3][tid];
        if (tid == 0) { pr[0] = red[0]; pr[1] = red[1]; }

        // ---- last chunk of row r runs the critic head ----
        __threadfence();
        __syncthreads();
        if (tid == 0)
            *sflag = (atomicAdd(&cnt[r], 1) == CH_ - 1) ? 1 : 0;
        __syncthreads();
        if (*sflag) {
            __threadfence();
            float* gbar = (float*)smem;          // xt dead; reuse
            float* red2 = (float*)(smem + 512);
            const float* prr = part + (long)r * CH_ * (H_ + 2);
            if (tid < H_) {
                float mm = -1e30f;
                #pragma unroll
                for (int c = 0; c < CH_; ++c) mm = fmaxf(mm, prr[c * (H_ + 2)]);
                float gg = 0.f, ll = 0.f;
                #pragma unroll
                for (int c = 0; c < CH_; ++c) {
                    const float sfac = __expf(prr[c * (H_ + 2)] - mm);
                    ll += sfac * prr[c * (H_ + 2) + 1];
                    gg += sfac * prr[c * (H_ + 2) + 2 + tid];
                }
                gbar[tid] = gg / ll;
            }
            __syncthreads();
            if (tid < H_) {
                float t = b_crit1[tid];
                for (int i = 0; i < H_; ++i)
                    t = fmaf(gbar[i], W_crit1[i * H_ + tid], t);
                t = fmaxf(t, 0.f);
                float p = t * W_crit2[tid];
                #pragma unroll
                for (int o = 32; o > 0; o >>= 1) p += __shfl_xor(p, o);
                if ((tid & 63) == 0) red2[tid >> 6] = p;
            }
            __syncthreads();
            if (tid == 0) values[r] = red2[0] + red2[1] + b_crit2[0];
        }
    }
}

// ---------------------------------------------------------------------------
extern "C" void kernel_launch(void* const* d_in, const int* in_sizes, int n_in,
                              void* d_out, int out_size, void* d_ws, size_t ws_size,
                              hipStream_t stream)
{
    const float* x        = (const float*)d_in[0];
    const int*   cand_idx = (const int*)d_in[2];
    const int*   comp_idx = (const int*)d_in[4];
    const float* W_enc_a  = (const float*)d_in[6];
    const float* b_enc_a  = (const float*)d_in[7];
    const float* W_enc_c  = (const float*)d_in[8];
    const float* b_enc_c  = (const float*)d_in[9];
    const float* ln_g     = (const float*)d_in[10];
    const float* ln_b     = (const float*)d_in[11];
    const float* W_actor  = (const float*)d_in[12];
    const float* b_actor  = (const float*)d_in[13];
    const float* W_phi1   = (const float*)d_in[14];
    const float* b_phi1   = (const float*)d_in[15];
    const float* W_phi2   = (const float*)d_in[16];
    const float* b_phi2   = (const float*)d_in[17];
    const float* w_score  = (const float*)d_in[18];
    const float* w_comp   = (const float*)d_in[19];
    const float* comp_bias= (const float*)d_in[20];
    const float* w_attn   = (const float*)d_in[21];
    const float* b_attn   = (const float*)d_in[22];
    const float* W_crit1  = (const float*)d_in[23];
    const float* b_crit1  = (const float*)d_in[24];
    const float* W_crit2  = (const float*)d_in[25];
    const float* b_crit2  = (const float*)d_in[26];

    float* logits = (float*)d_out;           // [R_*K_]
    float* values = logits + R_ * K_;        // [R_]

    float* part = (float*)d_ws;
    unsigned short* wsW1 = (unsigned short*)((char*)d_ws + (size_t)PART_FLOATS * 4);
    unsigned short* wsW2 = wsW1 + W1_USHORTS;
    unsigned short* wsWe = wsW2 + W2_USHORTS;
    int* cnt = (int*)(wsWe + WE_USHORTS);

    prep_kernel<<<(W1_USHORTS + 255) / 256, 256, 0, stream>>>(
        W_phi1, W_phi2, W_enc_c, wsW1, wsW2, wsWe, cnt);

    // even blocks: 4096 actor (4 rk-waves each); odd blocks: 4096 critic chunks
    fused_kernel<<<8192, 256, 0, stream>>>(
        x, cand_idx, comp_idx,
        W_enc_a, b_enc_a, b_enc_c, ln_g, ln_b, W_actor, b_actor,
        b_phi1, b_phi2, w_score, w_comp, comp_bias,
        w_attn, b_attn, W_crit1, b_crit1, W_crit2, b_crit2,
        wsW1, wsW2, wsWe, part, cnt, logits, values);
}

// Round 5
// 388.119 us; speedup vs baseline: 3.6101x; 3.6101x over previous
//
#include <hip/hip_runtime.h>
#include <hip/hip_bf16.h>

// Problem constants
#define R_ 256
#define N_ 2048
#define K_ 64
#define C_ 16
#define D_ 64
#define H_ 128
#define EPS_ 1e-5f

// Critic partitioning: 16 chunks of 128 nodes
#define CH_ 16
#define NB_ 128

// LDS row strides (ushorts). 16B-aligned rows; non-pow2 shift vs banks.
#define XST_ 72     // rows of 64 bf16
#define TST_ 136    // rows of 128 bf16

typedef short bf16x8 __attribute__((ext_vector_type(8)));
typedef float f32x4  __attribute__((ext_vector_type(4)));

__device__ __forceinline__ unsigned short f2b(float f) {
    union { float f; unsigned int u; } v; v.f = f;
    unsigned int u = v.u;
    unsigned int r = (u + 0x7FFFu + ((u >> 16) & 1u)) >> 16;
    return (unsigned short)r;
}
__device__ __forceinline__ unsigned int pk2(float a, float b) {
    return (unsigned int)f2b(a) | ((unsigned int)f2b(b) << 16);
}

// workspace layout:
//   part : R_*CH_*(H_+2) floats
//   wsW1 : 24576 ushort (B-frag swizzled W_phi1)
//   wsW2 : 16384 ushort
//   wsWe : 8192 ushort  (W_enc_c)
#define PART_FLOATS (R_ * CH_ * (H_ + 2))
#define W1_USHORTS  24576
#define W2_USHORTS  16384
#define WE_USHORTS  8192

// Fused-kernel LDS: critic needs 21512 B; actor 4 waves x 4608 B = 18432 B
// (t1 overlaps dead xrow/hnb/xc regions - safe by data dependence: every t1
// ds_write's data depends on all prior ds_reads of the overlapped region).
#define AW_STRIDE 4608
#define SMEM_BYTES 21520

// ---------------------------------------------------------------------------
// Prep: fp32 weights -> bf16, pre-swizzled per-lane B-fragment order.
// out[(nt*KS+ks)*512 + l*8 + j] = W[ks*32 + (l>>4)*8 + j][nt*16 + (l&15)]
// ---------------------------------------------------------------------------
__global__ __launch_bounds__(256) void prep_kernel(
    const float* __restrict__ W_phi1, const float* __restrict__ W_phi2,
    const float* __restrict__ W_enc_c,
    unsigned short* __restrict__ o1, unsigned short* __restrict__ o2,
    unsigned short* __restrict__ oe)
{
    const int i = blockIdx.x * 256 + threadIdx.x;
    const int j = i & 7, l = (i >> 3) & 63, t = i >> 9;
    const int k_off = ((l >> 4) << 3) + j;
    const int n_off = l & 15;
    if (i < W1_USHORTS) {
        const int ks = t % 6, nt = t / 6;
        o1[i] = f2b(W_phi1[(ks * 32 + k_off) * H_ + nt * 16 + n_off]);
    }
    if (i < W2_USHORTS) {
        const int ks = t & 3, nt = t >> 2;
        o2[i] = f2b(W_phi2[(ks * 32 + k_off) * H_ + nt * 16 + n_off]);
    }
    if (i < WE_USHORTS) {
        const int ks = t & 1, nt = t >> 1;
        oe[i] = f2b(W_enc_c[(ks * 32 + k_off) * H_ + nt * 16 + n_off]);
    }
}

// ---------------------------------------------------------------------------
// Fused kernel. Even blocks: actor (4 independent waves, one (r,k) each,
// barrier-free). Odd blocks: critic partial for one (r, 128-node chunk).
// NO atomics / NO __threadfence (R4's agent-fence storm = 10x regression);
// cross-block visibility of `part` is provided by the kernel boundary.
// ---------------------------------------------------------------------------
__global__ __launch_bounds__(256) void fused_kernel(
    const float* __restrict__ x, const int* __restrict__ cand_idx,
    const int* __restrict__ comp_idx,
    const float* __restrict__ W_enc_a, const float* __restrict__ b_enc_a,
    const float* __restrict__ b_enc_c,
    const float* __restrict__ ln_g, const float* __restrict__ ln_b,
    const float* __restrict__ W_actor, const float* __restrict__ b_actor,
    const float* __restrict__ b_phi1, const float* __restrict__ b_phi2,
    const float* __restrict__ w_score, const float* __restrict__ w_comp,
    const float* __restrict__ comp_bias,
    const float* __restrict__ w_attn, const float* __restrict__ b_attn,
    const unsigned short* __restrict__ wsW1, const unsigned short* __restrict__ wsW2,
    const unsigned short* __restrict__ wsWe,
    float* __restrict__ part,
    float* __restrict__ logits)
{
    __shared__ __align__(16) char smem[SMEM_BYTES];
    const int tid = threadIdx.x;
    const int wv = tid >> 6, lane = tid & 63;
    const int q = lane >> 4, ln15 = lane & 15;

    if ((blockIdx.x & 1) == 0) {
        // ================= ACTOR: wave wv handles rk =================
        const int rk = (blockIdx.x >> 1) * 4 + wv;
        const int r = rk >> 6;   // / K_
        char* wbase = smem + wv * AW_STRIDE;
        unsigned short* hnb  = (unsigned short*)wbase;              // [0,256)
        float*          xrow = (float*)(wbase + 256);               // [256,512)
        unsigned short* xc   = (unsigned short*)(wbase + 512);      // [512,2816)
        unsigned short* t1   = (unsigned short*)wbase;              // [0,4352) overlaps all

        // stage candidate row (fp32) — lanes 0..15
        const int ci = cand_idx[rk];
        if (lane < 16) {
            const float4 v = *(const float4*)&x[((long)r * N_ + ci) * D_ + lane * 4];
            *(float4*)&xrow[lane * 4] = v;
        }
        // stage 16 competitor rows (bf16)
        #pragma unroll
        for (int i = 0; i < 4; ++i) {
            const int flat = i * 64 + lane;
            const int c = flat >> 4, d0 = (flat & 15) * 4;
            const int idx = comp_idx[rk * C_ + c];
            const float4 v = *(const float4*)&x[((long)r * N_ + idx) * D_ + d0];
            uint2 w; w.x = pk2(v.x, v.y); w.y = pk2(v.z, v.w);
            *(uint2*)&xc[c * XST_ + d0] = w;
        }
        __builtin_amdgcn_wave_barrier();

        // fp32 encode at candidate: lane -> h = lane, lane+64
        float h0 = b_enc_a[lane], h1 = b_enc_a[lane + 64];
        #pragma unroll 8
        for (int d = 0; d < D_; ++d) {
            const float xv = xrow[d];   // LDS broadcast
            h0 = fmaf(xv, W_enc_a[d * H_ + lane], h0);
            h1 = fmaf(xv, W_enc_a[d * H_ + 64 + lane], h1);
        }
        h0 = fmaxf(h0, 0.f); h1 = fmaxf(h1, 0.f);

        // LayerNorm (wave butterfly)
        float s = h0 + h1, s2 = h0 * h0 + h1 * h1;
        #pragma unroll
        for (int o = 1; o <= 32; o <<= 1) {
            s  += __shfl_xor(s, o);
            s2 += __shfl_xor(s2, o);
        }
        const float mu = s * (1.f / H_);
        const float rstd = rsqrtf(s2 * (1.f / H_) - mu * mu + EPS_);
        const float v0 = (h0 - mu) * rstd * ln_g[lane]      + ln_b[lane];
        const float v1 = (h1 - mu) * rstd * ln_g[lane + 64] + ln_b[lane + 64];
        hnb[lane]      = f2b(v0);
        hnb[lane + 64] = f2b(v1);

        // base head
        float base_l = v0 * W_actor[lane] + v1 * W_actor[lane + 64];
        #pragma unroll
        for (int o = 1; o <= 32; o <<= 1) base_l += __shfl_xor(base_l, o);
        __builtin_amdgcn_wave_barrier();

        // phi1 MFMA: A=[16x192] rows = [hn | xc_c]; all 8 n-tiles this wave
        bf16x8 a1[6];
        #pragma unroll
        for (int ks = 0; ks < 4; ++ks)
            a1[ks] = *(const bf16x8*)&hnb[ks * 32 + q * 8];        // broadcast rows
        #pragma unroll
        for (int ks = 0; ks < 2; ++ks)
            a1[4 + ks] = *(const bf16x8*)&xc[ln15 * XST_ + ks * 32 + q * 8];
        __builtin_amdgcn_wave_barrier();   // all ds_reads of hnb/xc issued before t1 writes

        const bf16x8* W1f = (const bf16x8*)wsW1;
        const bf16x8* W2f = (const bf16x8*)wsW2;

        f32x4 acc1[8];
        #pragma unroll
        for (int nt = 0; nt < 8; ++nt) acc1[nt] = (f32x4){0.f,0.f,0.f,0.f};
        #pragma unroll
        for (int nt = 0; nt < 8; ++nt)
            #pragma unroll
            for (int ks = 0; ks < 6; ++ks) {
                const bf16x8 b = W1f[(nt * 6 + ks) * 64 + lane];
                acc1[nt] = __builtin_amdgcn_mfma_f32_16x16x32_bf16(a1[ks], b, acc1[nt], 0, 0, 0);
            }
        // bias + relu -> t1 (bf16), C/D layout: row=q*4+reg (comp), col=h
        #pragma unroll
        for (int nt = 0; nt < 8; ++nt) {
            const int h = nt * 16 + ln15;
            const float b1 = b_phi1[h];
            #pragma unroll
            for (int reg = 0; reg < 4; ++reg)
                t1[(q * 4 + reg) * TST_ + h] = f2b(fmaxf(acc1[nt][reg] + b1, 0.f));
        }
        __builtin_amdgcn_wave_barrier();

        // phi2 MFMA: [16x128]@[128x128]
        bf16x8 a2[4];
        #pragma unroll
        for (int ks = 0; ks < 4; ++ks)
            a2[ks] = *(const bf16x8*)&t1[ln15 * TST_ + ks * 32 + q * 8];
        f32x4 acc2[8];
        #pragma unroll
        for (int nt = 0; nt < 8; ++nt) acc2[nt] = (f32x4){0.f,0.f,0.f,0.f};
        #pragma unroll
        for (int nt = 0; nt < 8; ++nt)
            #pragma unroll
            for (int ks = 0; ks < 4; ++ks) {
                const bf16x8 b = W2f[(nt * 4 + ks) * 64 + lane];
                acc2[nt] = __builtin_amdgcn_mfma_f32_16x16x32_bf16(a2[ks], b, acc2[nt], 0, 0, 0);
            }

        // heads: s[c] = z2.w_score, q[c] = z2.w_comp (z2 = acc2 + b_phi2)
        float sp[4] = {0.f,0.f,0.f,0.f}, qp[4] = {0.f,0.f,0.f,0.f};
        #pragma unroll
        for (int nt = 0; nt < 8; ++nt) {
            const int h = nt * 16 + ln15;
            const float ws = w_score[h], wc = w_comp[h], b2 = b_phi2[h];
            #pragma unroll
            for (int reg = 0; reg < 4; ++reg) {
                const float z = acc2[nt][reg] + b2;
                sp[reg] = fmaf(z, ws, sp[reg]);
                qp[reg] = fmaf(z, wc, qp[reg]);
            }
        }
        #pragma unroll
        for (int reg = 0; reg < 4; ++reg)
            #pragma unroll
            for (int m = 1; m <= 8; m <<= 1) {
                sp[reg] += __shfl_xor(sp[reg], m);
                qp[reg] += __shfl_xor(qp[reg], m);
            }
        // softmax over 16 comps distributed as c = q*4+reg
        float mloc = fmaxf(fmaxf(sp[0], sp[1]), fmaxf(sp[2], sp[3]));
        mloc = fmaxf(mloc, __shfl_xor(mloc, 16));
        mloc = fmaxf(mloc, __shfl_xor(mloc, 32));
        float S = 0.f, V = 0.f;
        #pragma unroll
        for (int reg = 0; reg < 4; ++reg) {
            const float e = __expf(sp[reg] - mloc);
            S += e; V = fmaf(e, qp[reg], V);
        }
        S += __shfl_xor(S, 16); S += __shfl_xor(S, 32);
        V += __shfl_xor(V, 16); V += __shfl_xor(V, 32);
        if (lane == 0)
            logits[rk] = base_l + V / S + comp_bias[0];

    } else {
        // ================= CRITIC: block = (r, 128-node chunk) =================
        const int cid = blockIdx.x >> 1;
        const int r = cid >> 4, ch = cid & 15;
        unsigned short* xt = (unsigned short*)smem;            // 18432 B
        float* sc    = (float*)(smem + 18432);                 // 512 B
        float* ebuf  = (float*)(smem + 18944);                 // 512 B
        float (*gbuf)[H_] = (float(*)[H_])(smem + 19456);      // 2048 B
        float* red   = (float*)(smem + 21504);                 // 8 B

        // stage x chunk -> bf16 LDS
        const float4* xb = (const float4*)(x + ((long)r * N_ + (long)ch * NB_) * D_);
        for (int i = tid; i < NB_ * 16; i += 256) {
            const int row = i >> 4, d0 = (i & 15) * 4;
            const float4 v = xb[i];
            uint2 w; w.x = pk2(v.x, v.y); w.y = pk2(v.z, v.w);
            *(uint2*)&xt[row * XST_ + d0] = w;
        }
        __syncthreads();

        bf16x8 A[2][2];
        #pragma unroll
        for (int mti = 0; mti < 2; ++mti) {
            const int node = (wv * 2 + mti) * 16 + ln15;
            #pragma unroll
            for (int ks = 0; ks < 2; ++ks)
                A[mti][ks] = *(const bf16x8*)&xt[node * XST_ + ks * 32 + q * 8];
        }
        float wa[8], be[8];
        #pragma unroll
        for (int nt = 0; nt < 8; ++nt) {
            wa[nt] = w_attn[nt * 16 + ln15];
            be[nt] = b_enc_c[nt * 16 + ln15];
        }
        const float batt = b_attn[0];
        const bf16x8* Wef = (const bf16x8*)wsWe;
        f32x4 acc[2][8];
        #pragma unroll
        for (int mti = 0; mti < 2; ++mti)
            #pragma unroll
            for (int nt = 0; nt < 8; ++nt)
                acc[mti][nt] = (f32x4){0.f,0.f,0.f,0.f};
        #pragma unroll
        for (int nt = 0; nt < 8; ++nt)
            #pragma unroll
            for (int ks = 0; ks < 2; ++ks) {
                const bf16x8 b = Wef[(nt * 2 + ks) * 64 + lane];
                acc[0][nt] = __builtin_amdgcn_mfma_f32_16x16x32_bf16(A[0][ks], b, acc[0][nt], 0, 0, 0);
                acc[1][nt] = __builtin_amdgcn_mfma_f32_16x16x32_bf16(A[1][ks], b, acc[1][nt], 0, 0, 0);
            }
        #pragma unroll
        for (int mti = 0; mti < 2; ++mti)
            #pragma unroll
            for (int nt = 0; nt < 8; ++nt)
                #pragma unroll
                for (int reg = 0; reg < 4; ++reg)
                    acc[mti][nt][reg] = fmaxf(acc[mti][nt][reg] + be[nt], 0.f);

        // sc[node] = h.w_attn + b_attn
        #pragma unroll
        for (int mti = 0; mti < 2; ++mti)
            #pragma unroll
            for (int reg = 0; reg < 4; ++reg) {
                float sv = 0.f;
                #pragma unroll
                for (int nt = 0; nt < 8; ++nt)
                    sv = fmaf(acc[mti][nt][reg], wa[nt], sv);
                #pragma unroll
                for (int m = 1; m <= 8; m <<= 1) sv += __shfl_xor(sv, m);
                if (ln15 == 0)
                    sc[(wv * 2 + mti) * 16 + q * 4 + reg] = sv + batt;
            }
        __syncthreads();

        if (tid < 64) {
            const float u0 = sc[tid], u1 = sc[tid + 64];
            float m = fmaxf(u0, u1);
            #pragma unroll
            for (int o = 1; o <= 32; o <<= 1) m = fmaxf(m, __shfl_xor(m, o));
            float ssum = __expf(u0 - m) + __expf(u1 - m);
            #pragma unroll
            for (int o = 1; o <= 32; o <<= 1) ssum += __shfl_xor(ssum, o);
            if (tid == 0) { red[0] = m; red[1] = ssum; }
        }
        __syncthreads();
        const float mstar = red[0];
        if (tid < NB_) ebuf[tid] = __expf(sc[tid] - mstar);
        __syncthreads();

        float gp[8] = {0.f,0.f,0.f,0.f,0.f,0.f,0.f,0.f};
        #pragma unroll
        for (int mti = 0; mti < 2; ++mti)
            #pragma unroll
            for (int reg = 0; reg < 4; ++reg) {
                const float e = ebuf[(wv * 2 + mti) * 16 + q * 4 + reg];
                #pragma unroll
                for (int nt = 0; nt < 8; ++nt)
                    gp[nt] = fmaf(e, acc[mti][nt][reg], gp[nt]);
            }
        #pragma unroll
        for (int nt = 0; nt < 8; ++nt) {
            float v = gp[nt];
            v += __shfl_xor(v, 16);
            v += __shfl_xor(v, 32);
            if (q == 0) gbuf[wv][nt * 16 + ln15] = v;
        }
        __syncthreads();

        float* pr = part + ((long)r * CH_ + ch) * (H_ + 2);
        if (tid < H_)
            pr[2 + tid] = gbuf[0][tid] + gbuf[1][tid] + gbuf[2][tid] + gbuf[3][tid];
        if (tid == 0) { pr[0] = red[0]; pr[1] = red[1]; }
    }
}

// ---------------------------------------------------------------------------
// Critic finalize: one block per r. Merge CH_ partials, critic MLP head (fp32).
// ---------------------------------------------------------------------------
__global__ __launch_bounds__(128) void critic_final_kernel(
    const float* __restrict__ part,
    const float* __restrict__ W_crit1, const float* __restrict__ b_crit1,
    const float* __restrict__ W_crit2, const float* __restrict__ b_crit2,
    float* __restrict__ values)
{
    const int r = blockIdx.x;
    const int tid = threadIdx.x;
    __shared__ float gbar[H_];
    __shared__ float red[2];

    const float* pr = part + (long)r * CH_ * (H_ + 2);
    float mstar = -1e30f;
    #pragma unroll
    for (int c = 0; c < CH_; ++c) mstar = fmaxf(mstar, pr[c * (H_ + 2)]);
    float gg = 0.f, ll = 0.f;
    #pragma unroll
    for (int c = 0; c < CH_; ++c) {
        const float s = __expf(pr[c * (H_ + 2)] - mstar);
        ll += s * pr[c * (H_ + 2) + 1];
        gg += s * pr[c * (H_ + 2) + 2 + tid];
    }
    gbar[tid] = gg / ll;
    __syncthreads();

    float t = b_crit1[tid];
    for (int i = 0; i < H_; ++i)
        t = fmaf(gbar[i], W_crit1[i * H_ + tid], t);
    t = fmaxf(t, 0.f);
    float p = t * W_crit2[tid];
    #pragma unroll
    for (int o = 32; o > 0; o >>= 1) p += __shfl_xor(p, o);
    if ((tid & 63) == 0) red[tid >> 6] = p;
    __syncthreads();
    if (tid == 0) values[r] = red[0] + red[1] + b_crit2[0];
}

// ---------------------------------------------------------------------------
extern "C" void kernel_launch(void* const* d_in, const int* in_sizes, int n_in,
                              void* d_out, int out_size, void* d_ws, size_t ws_size,
                              hipStream_t stream)
{
    const float* x        = (const float*)d_in[0];
    const int*   cand_idx = (const int*)d_in[2];
    const int*   comp_idx = (const int*)d_in[4];
    const float* W_enc_a  = (const float*)d_in[6];
    const float* b_enc_a  = (const float*)d_in[7];
    const float* W_enc_c  = (const float*)d_in[8];
    const float* b_enc_c  = (const float*)d_in[9];
    const float* ln_g     = (const float*)d_in[10];
    const float* ln_b     = (const float*)d_in[11];
    const float* W_actor  = (const float*)d_in[12];
    const float* b_actor  = (const float*)d_in[13];
    const float* W_phi1   = (const float*)d_in[14];
    const float* b_phi1   = (const float*)d_in[15];
    const float* W_phi2   = (const float*)d_in[16];
    const float* b_phi2   = (const float*)d_in[17];
    const float* w_score  = (const float*)d_in[18];
    const float* w_comp   = (const float*)d_in[19];
    const float* comp_bias= (const float*)d_in[20];
    const float* w_attn   = (const float*)d_in[21];
    const float* b_attn   = (const float*)d_in[22];
    const float* W_crit1  = (const float*)d_in[23];
    const float* b_crit1  = (const float*)d_in[24];
    const float* W_crit2  = (const float*)d_in[25];
    const float* b_crit2  = (const float*)d_in[26];

    float* logits = (float*)d_out;           // [R_*K_]
    float* values = logits + R_ * K_;        // [R_]

    float* part = (float*)d_ws;
    unsigned short* wsW1 = (unsigned short*)((char*)d_ws + (size_t)PART_FLOATS * 4);
    unsigned short* wsW2 = wsW1 + W1_USHORTS;
    unsigned short* wsWe = wsW2 + W2_USHORTS;

    prep_kernel<<<(W1_USHORTS + 255) / 256, 256, 0, stream>>>(
        W_phi1, W_phi2, W_enc_c, wsW1, wsW2, wsWe);

    // even blocks: 4096 actor (4 rk-waves each); odd blocks: 4096 critic chunks
    fused_kernel<<<8192, 256, 0, stream>>>(
        x, cand_idx, comp_idx,
        W_enc_a, b_enc_a, b_enc_c, ln_g, ln_b, W_actor, b_actor,
        b_phi1, b_phi2, w_score, w_comp, comp_bias,
        w_attn, b_attn, wsW1, wsW2, wsWe, part, logits);

    critic_final_kernel<<<R_, 128, 0, stream>>>(
        part, W_crit1, b_crit1, W_crit2, b_crit2, values);
}